// Round 6
// baseline (32.088 us; speedup 1.0000x reference)
//
#include <hip/hip_runtime.h>

// MultiLevelEmbedding: out[b,t,:] = emb_tables[level_ids[b,t], token_ids[b,t], :]
//                                 + level_embed[level_ids[b,t], :]
// B=64, T=1024, L=4, VOCAB=258, D=512, fp32.
// HBM-write-bound: 128 MiB out-stream; tables (2.1 MiB) L2-resident.
//
// Round-6 = round-3 EXACTLY (27.4 us best: strided wave<->row, readfirstlane
// scalar indices, 2-row unroll) with ONE variable flipped: regular stores
// instead of nontemporal. Unbundles round 4's two-variable regression.
//  - wave w owns rows {w + j*nw}: write front stays a dense moving band.
//  - lane l covers f4 elems l and l+64 -> two coalesced 1 KiB accesses/row.

#define MLE_D     512
#define MLE_D4    128   // float4 per row
#define MLE_VOCAB 258

typedef float f32x4 __attribute__((ext_vector_type(4)));

__global__ __launch_bounds__(256) void MultiLevelEmbedding_34437047780006_kernel(
    const int* __restrict__ level_ids,
    const int* __restrict__ token_ids,
    const float* __restrict__ emb_tables,
    const float* __restrict__ level_embed,
    float* __restrict__ out,
    int nrows)
{
    const int lane = (int)(threadIdx.x & 63);
    const int wib  = __builtin_amdgcn_readfirstlane((int)(threadIdx.x >> 6));
    const int nw   = (int)gridDim.x * 4;            // total waves
    int gw = (int)blockIdx.x * 4 + wib;             // this wave's id (SGPR)

    const f32x4* __restrict__ levv = reinterpret_cast<const f32x4*>(level_embed);

    int row = gw;
    // 2 rows per iteration: two independent idx->table chains in flight.
    for (; row + nw < nrows; row += 2 * nw) {
        const int r0 = row;
        const int r1 = row + nw;
        const int lvl0 = __builtin_amdgcn_readfirstlane(level_ids[r0]);
        const int tok0 = __builtin_amdgcn_readfirstlane(token_ids[r0]);
        const int lvl1 = __builtin_amdgcn_readfirstlane(level_ids[r1]);
        const int tok1 = __builtin_amdgcn_readfirstlane(token_ids[r1]);

        const f32x4* __restrict__ t0 = reinterpret_cast<const f32x4*>(
            emb_tables + (long long)(lvl0 * MLE_VOCAB + tok0) * MLE_D);
        const f32x4* __restrict__ t1 = reinterpret_cast<const f32x4*>(
            emb_tables + (long long)(lvl1 * MLE_VOCAB + tok1) * MLE_D);

        f32x4 a0 = t0[lane];
        f32x4 b0 = t0[lane + 64];
        f32x4 a1 = t1[lane];
        f32x4 b1 = t1[lane + 64];

        f32x4 la0 = levv[lvl0 * MLE_D4 + lane];
        f32x4 lb0 = levv[lvl0 * MLE_D4 + lane + 64];
        f32x4 la1 = levv[lvl1 * MLE_D4 + lane];
        f32x4 lb1 = levv[lvl1 * MLE_D4 + lane + 64];

        f32x4* __restrict__ o0 = reinterpret_cast<f32x4*>(out + (long long)r0 * MLE_D);
        f32x4* __restrict__ o1 = reinterpret_cast<f32x4*>(out + (long long)r1 * MLE_D);

        o0[lane]      = a0 + la0;
        o0[lane + 64] = b0 + lb0;
        o1[lane]      = a1 + la1;
        o1[lane + 64] = b1 + lb1;
    }
    // tail (at most one row per wave)
    for (; row < nrows; row += nw) {
        const int lvl = __builtin_amdgcn_readfirstlane(level_ids[row]);
        const int tok = __builtin_amdgcn_readfirstlane(token_ids[row]);
        const f32x4* __restrict__ t = reinterpret_cast<const f32x4*>(
            emb_tables + (long long)(lvl * MLE_VOCAB + tok) * MLE_D);
        f32x4 a = t[lane];
        f32x4 b = t[lane + 64];
        f32x4 la = levv[lvl * MLE_D4 + lane];
        f32x4 lb = levv[lvl * MLE_D4 + lane + 64];
        f32x4* __restrict__ o = reinterpret_cast<f32x4*>(out + (long long)row * MLE_D);
        o[lane]      = a + la;
        o[lane + 64] = b + lb;
    }
}

extern "C" void kernel_launch(void* const* d_in, const int* in_sizes, int n_in,
                              void* d_out, int out_size, void* d_ws, size_t ws_size,
                              hipStream_t stream) {
    const int*   level_ids   = (const int*)d_in[0];
    const int*   token_ids   = (const int*)d_in[1];
    const float* emb_tables  = (const float*)d_in[2];
    const float* level_embed = (const float*)d_in[3];
    float*       out         = (float*)d_out;

    const int nrows = in_sizes[0];   // B*T = 65536

    const int block = 256;           // 4 waves/block
    int grid = 2048;                 // 8192 waves -> 8 rows/wave
    int max_blocks = (nrows + 3) / 4;
    if (grid > max_blocks) grid = max_blocks;

    MultiLevelEmbedding_34437047780006_kernel<<<grid, block, 0, stream>>>(
        level_ids, token_ids, emb_tables, level_embed, out, nrows);
}

// Round 7
// 29.175 us; speedup vs baseline: 1.0998x; 1.0998x over previous
//
#include <hip/hip_runtime.h>

// MultiLevelEmbedding: out[b,t,:] = emb_tables[level_ids[b,t], token_ids[b,t], :]
//                                 + level_embed[level_ids[b,t], :]
// B=64, T=1024, L=4, VOCAB=258, D=512, fp32.
// HBM-write-bound: 128 MiB out-stream; tables (2.1 MiB) L2-resident.
//
// Round-7 = round-3 (27.4 us best) with ONE change: 4 rows in flight per
// iteration instead of 2 (deeper memory-level parallelism; 4 independent
// idx->gather->add->store chains). Everything else confirmed by A/B:
//  - NONTEMPORAL stores (R6: regular stores cost +4.7 us -- the allocating
//    write stream evicts the tables from per-XCD L2).
//  - strided wave<->row map (R4: slab assignment cost ~4 us).
//  - per-iteration readfirstlane scalar indices (R5: hoisting was neutral).
//  - lane l covers f4 elems l and l+64 -> two coalesced 1 KiB accesses/row.

#define MLE_D     512
#define MLE_D4    128   // float4 per row
#define MLE_VOCAB 258

typedef float f32x4 __attribute__((ext_vector_type(4)));

__global__ __launch_bounds__(256) void MultiLevelEmbedding_34437047780006_kernel(
    const int* __restrict__ level_ids,
    const int* __restrict__ token_ids,
    const float* __restrict__ emb_tables,
    const float* __restrict__ level_embed,
    float* __restrict__ out,
    int nrows)
{
    const int lane = (int)(threadIdx.x & 63);
    const int wib  = __builtin_amdgcn_readfirstlane((int)(threadIdx.x >> 6));
    const int nw   = (int)gridDim.x * 4;            // total waves
    const int gw   = (int)blockIdx.x * 4 + wib;     // this wave's id (SGPR)

    const f32x4* __restrict__ levv = reinterpret_cast<const f32x4*>(level_embed);

    int row = gw;
    // 4 rows per iteration: four independent gather chains in flight.
    for (; row + 3 * nw < nrows; row += 4 * nw) {
        const int r0 = row;
        const int r1 = row + nw;
        const int r2 = row + 2 * nw;
        const int r3 = row + 3 * nw;

        const int lvl0 = __builtin_amdgcn_readfirstlane(level_ids[r0]);
        const int tok0 = __builtin_amdgcn_readfirstlane(token_ids[r0]);
        const int lvl1 = __builtin_amdgcn_readfirstlane(level_ids[r1]);
        const int tok1 = __builtin_amdgcn_readfirstlane(token_ids[r1]);
        const int lvl2 = __builtin_amdgcn_readfirstlane(level_ids[r2]);
        const int tok2 = __builtin_amdgcn_readfirstlane(token_ids[r2]);
        const int lvl3 = __builtin_amdgcn_readfirstlane(level_ids[r3]);
        const int tok3 = __builtin_amdgcn_readfirstlane(token_ids[r3]);

        const f32x4* __restrict__ t0 = reinterpret_cast<const f32x4*>(
            emb_tables + (long long)(lvl0 * MLE_VOCAB + tok0) * MLE_D);
        const f32x4* __restrict__ t1 = reinterpret_cast<const f32x4*>(
            emb_tables + (long long)(lvl1 * MLE_VOCAB + tok1) * MLE_D);
        const f32x4* __restrict__ t2 = reinterpret_cast<const f32x4*>(
            emb_tables + (long long)(lvl2 * MLE_VOCAB + tok2) * MLE_D);
        const f32x4* __restrict__ t3 = reinterpret_cast<const f32x4*>(
            emb_tables + (long long)(lvl3 * MLE_VOCAB + tok3) * MLE_D);

        // all 8 table loads in flight before any consumer
        f32x4 a0 = t0[lane];  f32x4 b0 = t0[lane + 64];
        f32x4 a1 = t1[lane];  f32x4 b1 = t1[lane + 64];
        f32x4 a2 = t2[lane];  f32x4 b2 = t2[lane + 64];
        f32x4 a3 = t3[lane];  f32x4 b3 = t3[lane + 64];

        f32x4 la0 = levv[lvl0 * MLE_D4 + lane];
        f32x4 lb0 = levv[lvl0 * MLE_D4 + lane + 64];
        f32x4 la1 = levv[lvl1 * MLE_D4 + lane];
        f32x4 lb1 = levv[lvl1 * MLE_D4 + lane + 64];
        f32x4 la2 = levv[lvl2 * MLE_D4 + lane];
        f32x4 lb2 = levv[lvl2 * MLE_D4 + lane + 64];
        f32x4 la3 = levv[lvl3 * MLE_D4 + lane];
        f32x4 lb3 = levv[lvl3 * MLE_D4 + lane + 64];

        f32x4* __restrict__ o0 = reinterpret_cast<f32x4*>(out + (long long)r0 * MLE_D);
        f32x4* __restrict__ o1 = reinterpret_cast<f32x4*>(out + (long long)r1 * MLE_D);
        f32x4* __restrict__ o2 = reinterpret_cast<f32x4*>(out + (long long)r2 * MLE_D);
        f32x4* __restrict__ o3 = reinterpret_cast<f32x4*>(out + (long long)r3 * MLE_D);

        __builtin_nontemporal_store(a0 + la0, o0 + lane);
        __builtin_nontemporal_store(b0 + lb0, o0 + lane + 64);
        __builtin_nontemporal_store(a1 + la1, o1 + lane);
        __builtin_nontemporal_store(b1 + lb1, o1 + lane + 64);
        __builtin_nontemporal_store(a2 + la2, o2 + lane);
        __builtin_nontemporal_store(b2 + lb2, o2 + lane + 64);
        __builtin_nontemporal_store(a3 + la3, o3 + lane);
        __builtin_nontemporal_store(b3 + lb3, o3 + lane + 64);
    }
    // tail (generic per-row)
    for (; row < nrows; row += nw) {
        const int lvl = __builtin_amdgcn_readfirstlane(level_ids[row]);
        const int tok = __builtin_amdgcn_readfirstlane(token_ids[row]);
        const f32x4* __restrict__ t = reinterpret_cast<const f32x4*>(
            emb_tables + (long long)(lvl * MLE_VOCAB + tok) * MLE_D);
        f32x4 a = t[lane];
        f32x4 b = t[lane + 64];
        f32x4 la = levv[lvl * MLE_D4 + lane];
        f32x4 lb = levv[lvl * MLE_D4 + lane + 64];
        f32x4* __restrict__ o = reinterpret_cast<f32x4*>(out + (long long)row * MLE_D);
        __builtin_nontemporal_store(a + la, o + lane);
        __builtin_nontemporal_store(b + lb, o + lane + 64);
    }
}

extern "C" void kernel_launch(void* const* d_in, const int* in_sizes, int n_in,
                              void* d_out, int out_size, void* d_ws, size_t ws_size,
                              hipStream_t stream) {
    const int*   level_ids   = (const int*)d_in[0];
    const int*   token_ids   = (const int*)d_in[1];
    const float* emb_tables  = (const float*)d_in[2];
    const float* level_embed = (const float*)d_in[3];
    float*       out         = (float*)d_out;

    const int nrows = in_sizes[0];   // B*T = 65536

    const int block = 256;           // 4 waves/block
    int grid = 2048;                 // 8192 waves -> 8 rows/wave
    int max_blocks = (nrows + 3) / 4;
    if (grid > max_blocks) grid = max_blocks;

    MultiLevelEmbedding_34437047780006_kernel<<<grid, block, 0, stream>>>(
        level_ids, token_ids, emb_tables, level_embed, out, nrows);
}

// Round 8
// 27.361 us; speedup vs baseline: 1.1728x; 1.0663x over previous
//
#include <hip/hip_runtime.h>

// MultiLevelEmbedding: out[b,t,:] = emb_tables[level_ids[b,t], token_ids[b,t], :]
//                                 + level_embed[level_ids[b,t], :]
// B=64, T=1024, L=4, VOCAB=258, D=512, fp32.
// HBM-write-bound: 128 MiB out-stream; tables (2.1 MiB) L2-resident.
//
// FINAL (= round-3 config, 27.4 us; all levers A/B-isolated R4-R7):
//  - NONTEMPORAL stores: required. R6 A/B: regular (allocating) stores cost
//    +4.7 us -- the 128 MiB write stream evicts tables from per-XCD L2.
//  - STRIDED wave<->row map {w + j*nw}: required. R4 A/B: consecutive-slab
//    assignment cost ~4 us.
//  - readfirstlane scalar index loads: neutral (R5) but keeps VMEM count low.
//  - 2-row unroll: optimal. 4-deep (R7) was -1.8 us; hoisting 8 rows of
//    indices (R5) neutral. Latency is TLP-hidden at 32 waves/CU.
//  - lane l covers f4 elems l and l+64 -> two coalesced 1 KiB accesses/row.

#define MLE_D     512
#define MLE_D4    128   // float4 per row
#define MLE_VOCAB 258

typedef float f32x4 __attribute__((ext_vector_type(4)));

__global__ __launch_bounds__(256) void MultiLevelEmbedding_34437047780006_kernel(
    const int* __restrict__ level_ids,
    const int* __restrict__ token_ids,
    const float* __restrict__ emb_tables,
    const float* __restrict__ level_embed,
    float* __restrict__ out,
    int nrows)
{
    const int lane = (int)(threadIdx.x & 63);
    const int wib  = __builtin_amdgcn_readfirstlane((int)(threadIdx.x >> 6));
    const int nw   = (int)gridDim.x * 4;            // total waves
    int gw = (int)blockIdx.x * 4 + wib;             // this wave's id (SGPR)

    const f32x4* __restrict__ levv = reinterpret_cast<const f32x4*>(level_embed);

    int row = gw;
    // 2 rows per iteration: two independent idx->table chains in flight.
    for (; row + nw < nrows; row += 2 * nw) {
        const int r0 = row;
        const int r1 = row + nw;
        const int lvl0 = __builtin_amdgcn_readfirstlane(level_ids[r0]);
        const int tok0 = __builtin_amdgcn_readfirstlane(token_ids[r0]);
        const int lvl1 = __builtin_amdgcn_readfirstlane(level_ids[r1]);
        const int tok1 = __builtin_amdgcn_readfirstlane(token_ids[r1]);

        const f32x4* __restrict__ t0 = reinterpret_cast<const f32x4*>(
            emb_tables + (long long)(lvl0 * MLE_VOCAB + tok0) * MLE_D);
        const f32x4* __restrict__ t1 = reinterpret_cast<const f32x4*>(
            emb_tables + (long long)(lvl1 * MLE_VOCAB + tok1) * MLE_D);

        f32x4 a0 = t0[lane];
        f32x4 b0 = t0[lane + 64];
        f32x4 a1 = t1[lane];
        f32x4 b1 = t1[lane + 64];

        f32x4 la0 = levv[lvl0 * MLE_D4 + lane];
        f32x4 lb0 = levv[lvl0 * MLE_D4 + lane + 64];
        f32x4 la1 = levv[lvl1 * MLE_D4 + lane];
        f32x4 lb1 = levv[lvl1 * MLE_D4 + lane + 64];

        f32x4* __restrict__ o0 = reinterpret_cast<f32x4*>(out + (long long)r0 * MLE_D);
        f32x4* __restrict__ o1 = reinterpret_cast<f32x4*>(out + (long long)r1 * MLE_D);

        __builtin_nontemporal_store(a0 + la0, o0 + lane);
        __builtin_nontemporal_store(b0 + lb0, o0 + lane + 64);
        __builtin_nontemporal_store(a1 + la1, o1 + lane);
        __builtin_nontemporal_store(b1 + lb1, o1 + lane + 64);
    }
    // tail (at most one row per wave)
    for (; row < nrows; row += nw) {
        const int lvl = __builtin_amdgcn_readfirstlane(level_ids[row]);
        const int tok = __builtin_amdgcn_readfirstlane(token_ids[row]);
        const f32x4* __restrict__ t = reinterpret_cast<const f32x4*>(
            emb_tables + (long long)(lvl * MLE_VOCAB + tok) * MLE_D);
        f32x4 a = t[lane];
        f32x4 b = t[lane + 64];
        f32x4 la = levv[lvl * MLE_D4 + lane];
        f32x4 lb = levv[lvl * MLE_D4 + lane + 64];
        f32x4* __restrict__ o = reinterpret_cast<f32x4*>(out + (long long)row * MLE_D);
        __builtin_nontemporal_store(a + la, o + lane);
        __builtin_nontemporal_store(b + lb, o + lane + 64);
    }
}

extern "C" void kernel_launch(void* const* d_in, const int* in_sizes, int n_in,
                              void* d_out, int out_size, void* d_ws, size_t ws_size,
                              hipStream_t stream) {
    const int*   level_ids   = (const int*)d_in[0];
    const int*   token_ids   = (const int*)d_in[1];
    const float* emb_tables  = (const float*)d_in[2];
    const float* level_embed = (const float*)d_in[3];
    float*       out         = (float*)d_out;

    const int nrows = in_sizes[0];   // B*T = 65536

    const int block = 256;           // 4 waves/block
    int grid = 2048;                 // 8192 waves -> 8 rows/wave
    int max_blocks = (nrows + 3) / 4;
    if (grid > max_blocks) grid = max_blocks;

    MultiLevelEmbedding_34437047780006_kernel<<<grid, block, 0, stream>>>(
        level_ids, token_ids, emb_tables, level_embed, out, nrows);
}